// Round 8
// baseline (470.424 us; speedup 1.0000x reference)
//
#include <hip/hip_runtime.h>

// ---------------------------------------------------------------------------
// TransformerBlock on MI355X (gfx950) — round 12.
// Token-major: t = s*B + b, x is (8192, 1024).
// GEMM: T3 minimum 2-phase (measured neutral vs two-barrier r7 — kept; at
// 3 blk/CU the m114 cross-block overlap already hides staging).
// Attention v8: 2-blocks-per-CU restructure. Block = 384 thr (6 waves:
// 2 S-waves x 16 rows + 4 PV-waves x 128 dims), 32-row Q-tiles, LDS 71.7KB
// -> 2 blocks/CU (143KB). Grid (8 bh, 64 y) = 512 blocks. v7 was 1 blk/CU:
// every per-chunk barrier exposed full stage+LDS+L2 latency (MfmaUtil 17%).
// Two independent blocks interleave across barriers (m114 mechanism).
// Pairing: block y does (qt=y, first ceil((y+1)/2) chunks) then (qt=63-y,
// rest) -> 32-33 chunks/block. Same opart/lpart/combine contract.
// ws slots (MiB): S0[0,16) h/vt/m; S1[16,32) q/ctx; S2[32,48) k/g.lo;
// S3[48,64) vtmp/l/g.hi; [64,80) bf16 weights. d_out = attn partial scratch.
// ---------------------------------------------------------------------------

typedef __bf16 bf16;
typedef bf16 bf16x8 __attribute__((ext_vector_type(8)));
typedef bf16 bf16x4 __attribute__((ext_vector_type(4)));
typedef float f32x4 __attribute__((ext_vector_type(4)));

#define MFMA16x16x32(A, B, C) __builtin_amdgcn_mfma_f32_16x16x32_bf16(A, B, C, 0, 0, 0)

__device__ __forceinline__ void gload16(const void* g, void* l) {
  __builtin_amdgcn_global_load_lds(
      (const __attribute__((address_space(1))) void*)g,
      (__attribute__((address_space(3))) void*)l, 16, 0, 0);
}

// ---------------- f32 -> bf16 weight conversion (all 4 weights) ------------
__global__ __launch_bounds__(256) void wcvt4(
    const float* __restrict__ s0, bf16* __restrict__ d0,
    const float* __restrict__ s1, bf16* __restrict__ d1,
    const float* __restrict__ s2, bf16* __restrict__ d2,
    const float* __restrict__ s3, bf16* __restrict__ d3)
{
  const int gid = blockIdx.x * 256 + threadIdx.x;  // quad index, 2097152 total
  const float* s; bf16* d; int off;
  if (gid < 786432)       { s = s0; d = d0; off = gid; }
  else if (gid < 1048576) { s = s1; d = d1; off = gid - 786432; }
  else if (gid < 1572864) { s = s2; d = d2; off = gid - 1048576; }
  else                    { s = s3; d = d3; off = gid - 1572864; }
  const int i = off * 4;
  const float4 v = *(const float4*)(s + i);
  bf16x4 o;
  o[0] = (bf16)v.x; o[1] = (bf16)v.y; o[2] = (bf16)v.z; o[3] = (bf16)v.w;
  *(bf16x4*)(d + i) = o;
}

// ---------------- RMSNorm: (8192 x 1024) f32 -> bf16 -----------------------
__global__ __launch_bounds__(256) void rmsnorm_kernel(
    const float* __restrict__ x, const float* __restrict__ w, bf16* __restrict__ out)
{
  const int row = blockIdx.x;
  const int tid = threadIdx.x;
  const float4 v = *(const float4*)(x + (size_t)row * 1024 + tid * 4);
  float ss = v.x * v.x + v.y * v.y + v.z * v.z + v.w * v.w;
#pragma unroll
  for (int off = 1; off < 64; off <<= 1) ss += __shfl_xor(ss, off, 64);
  __shared__ float red[4];
  if ((tid & 63) == 0) red[tid >> 6] = ss;
  __syncthreads();
  const float tot = red[0] + red[1] + red[2] + red[3];
  const float inv = rsqrtf(tot * (1.0f / 1024.0f) + 1e-8f);
  const float4 g = *(const float4*)(w + tid * 4);
  bf16x4 o;
  o[0] = (bf16)(v.x * g.x * inv);
  o[1] = (bf16)(v.y * g.y * inv);
  o[2] = (bf16)(v.z * g.z * inv);
  o[3] = (bf16)(v.w * g.w * inv);
  *(bf16x4*)(out + (size_t)row * 1024 + tid * 4) = o;
}

// ---------------- GEMM: C = A * W^T + bias, 128x128, 2-phase ---------------
enum { EPI_BF16 = 0, EPI_RES = 1, EPI_GELU = 2, EPI_QKV = 3 };

template <int EPI>
__global__ __launch_bounds__(256, 3) void gemm_bt2(
    const bf16* __restrict__ A,   // M x K
    const bf16* __restrict__ B,   // N x K
    const float* __restrict__ bias,
    const float* res,             // may alias outF
    float* outF, bf16* outQ, bf16* outK, bf16* outV,
    int M, int N, int K)
{
  __shared__ bf16 lds[2][8192];  // 2 buffers x (As 4096 + Bs 4096) = 32 KB
  const int tid = threadIdx.x;
  // super-rows of 16 bm: concurrent blocks share a 4 MB A-slice (L2-resident)
  const int Nb = N >> 7;
  const int lin = blockIdx.x;
  const int sup = lin / (Nb << 4);
  const int rem = lin - sup * (Nb << 4);
  const int bm = (sup << 4) + (rem & 15);
  const int bn = rem >> 4;
  const int w = tid >> 6, lane = tid & 63;
  const int q = lane >> 4, lr = lane & 15;
  const int wr = (w >> 1) * 64, wc = (w & 1) * 64;
  f32x4 acc[4][4] = {};
  const int srow = lane >> 2;
  const int gch = ((lane & 3) - ((lane >> 3) & 3)) & 3;
  const bf16* Ab = A + (size_t)(bm * 128) * K;
  const bf16* Bb = B + (size_t)(bn * 128) * K;
  const int sw = ((q + (lr >> 1)) & 3) * 16;
  const int NK = K >> 5;

  // stage one BK=32 K-tile into buffer `dst` (4 gloads/thread: 2xA + 2xB)
#define STAGE(dst, k0)                                                        \
  {                                                                           \
    bf16* De = (dst);                                                         \
    _Pragma("unroll")                                                         \
    for (int c = 0; c < 2; c++) {                                             \
      const int r = (w * 2 + c) * 16 + srow;                                  \
      gload16(Ab + (size_t)r * K + (k0) + gch * 8, De + (w * 2 + c) * 512);   \
      gload16(Bb + (size_t)r * K + (k0) + gch * 8, De + 4096 + (w * 2 + c) * 512); \
    }                                                                         \
  }

  STAGE(&lds[0][0], 0);
  __syncthreads();  // tile 0 visible
#pragma unroll 1
  for (int u = 0; u < NK; ++u) {
    bf16* cur = &lds[u & 1][0];
    bf16* nxt = &lds[(u + 1) & 1][0];
    // T3 minimum 2-phase: issue next-tile stage FIRST, compute under it.
    // WAR-safe: nxt was read at u-1; every wave's __syncthreads at u-1's end
    // enforced lgkmcnt(0), so those reads completed before we got here.
    if (u + 1 < NK) STAGE(nxt, (u + 1) * 32);
    const char* As = (const char*)cur;
    const char* Bs = (const char*)(cur + 4096);
    bf16x8 af[4], bfr[4];
#pragma unroll
    for (int mt = 0; mt < 4; mt++)
      af[mt] = *(const bf16x8*)(As + (wr + mt * 16 + lr) * 64 + sw);
#pragma unroll
    for (int nt = 0; nt < 4; nt++)
      bfr[nt] = *(const bf16x8*)(Bs + (wc + nt * 16 + lr) * 64 + sw);
#pragma unroll
    for (int mt = 0; mt < 4; mt++)
#pragma unroll
      for (int nt = 0; nt < 4; nt++)
        acc[mt][nt] = MFMA16x16x32(af[mt], bfr[nt], acc[mt][nt]);
    // one barrier per K-tile; its vmcnt(0) drain lands after a full compute
    // phase covered the stage latency.
    __syncthreads();
  }
#undef STAGE

  const int gm0 = bm * 128 + wr + q * 4;
  const int gn0 = bn * 128 + wc + lr;
  bf16* outs = nullptr;
  if constexpr (EPI == EPI_QKV) {
    const int reg = (bn * 128) >> 10;
    outs = reg == 0 ? outQ : (reg == 1 ? outK : outV);
  } else {
    outs = outQ;
  }
#pragma unroll
  for (int nt = 0; nt < 4; nt++) {
    const int gn = gn0 + nt * 16;
    const float bv = bias[gn];
#pragma unroll
    for (int mt = 0; mt < 4; mt++) {
#pragma unroll
      for (int r = 0; r < 4; r++) {
        float v = acc[mt][nt][r] + bv;
        const int gm = gm0 + mt * 16 + r;
        if constexpr (EPI == EPI_GELU) {
          v = 0.5f * v * (1.0f + erff(v * 0.70710678118654752f));
          outs[(size_t)gm * N + gn] = (bf16)v;
        } else if constexpr (EPI == EPI_BF16) {
          outs[(size_t)gm * N + gn] = (bf16)v;
        } else if constexpr (EPI == EPI_QKV) {
          outs[(size_t)gm * 1024 + (gn & 1023)] = (bf16)v;
        } else {
          const size_t idx = (size_t)gm * N + gn;
          outF[idx] = v + res[idx];
        }
      }
    }
  }
}

// ---------------- V transpose: vtmp (t,n) -> vt[bh][dim][key] --------------
__global__ __launch_bounds__(256) void vtrans_kernel(
    const bf16* __restrict__ vtmp, bf16* __restrict__ vt)
{
  __shared__ bf16 tile[64 * 72];
  const int kt = blockIdx.x;
  const int dt = blockIdx.y;
  const int bh = blockIdx.z;
  const int b = bh >> 1, h = bh & 1;
  const int tid = threadIdx.x;
#pragma unroll
  for (int it = 0; it < 2; it++) {
    const int key = it * 32 + (tid >> 3);
    const int dc = (tid & 7) * 8;
    const bf16x8 v = *(const bf16x8*)(vtmp +
        (size_t)((kt * 64 + key) * 4 + b) * 1024 + h * 512 + dt * 64 + dc);
    *(bf16x8*)&tile[key * 72 + dc] = v;
  }
  __syncthreads();
#pragma unroll
  for (int it = 0; it < 2; it++) {
    const int dim = it * 32 + (tid >> 3);
    const int kc = (tid & 7) * 8;
    bf16x8 o;
#pragma unroll
    for (int j = 0; j < 8; j++) o[j] = tile[(kc + j) * 72 + dim];
    *(bf16x8*)(vt + (size_t)bh * (1u << 20) +
               (size_t)(dt * 64 + dim) * 2048 + kt * 64 + kc) = o;
  }
}

// ---------------- Attention v8: 6 waves, 2 blocks/CU -----------------------
// 384 threads: waves 0-1 = S-waves (rows [16w,16w+16) of a 32-row Q-tile),
// waves 2-5 = PV (dims [128(w-2),+128), O[2][8]=64 AGPR). Grid (8,64) = 512
// blocks = 2/CU; independent blocks interleave across per-chunk barriers.
// Block y: piece0 = (qt=y, chunks [0,hs)), piece1 = (qt=63-y, chunks
// [hs',nc')) where hs = ceil((qt+1)/2). Double-buffered Ks (stride 520,
// conflict-floor reads) and Ps; one barrier per chunk; S stages K[t+1],
// computes P[t]; PV consumes P[t-1].
__global__ __launch_bounds__(384, 3) void attn_kernel(
    const bf16* __restrict__ qb, const bf16* __restrict__ kb,
    const bf16* __restrict__ vtg, bf16* __restrict__ opart,
    float* __restrict__ lpart)
{
  __shared__ bf16 Ks[2][32 * 520];   // 2 x 33280 B
  __shared__ bf16 Ps[2][2][16 * 40]; // 2 x  2560 B  (71680 total -> 2 blk/CU)
  const int bh = blockIdx.x;          // 0..7 -> XCD affinity
  const int y = blockIdx.y;           // 0..63
  const int b = bh >> 1, h = bh & 1;
  const int tid = threadIdx.x;
  const int w = tid >> 6, lane = tid & 63;
  const int q = lane >> 4, lr = lane & 15;
  const float sc = 0.044194173824159216f;  // 1/sqrt(512)

  if (w < 2) {
    // ================= S-waves =================
    const bf16* krow0 = kb + (size_t)b * 1024 + h * 512 + lane * 8;  // per-lane 16B
    for (int piece = 0; piece < 2; ++piece) {
      const int qt = piece ? (63 - y) : y;
      const int qrow0 = qt * 32;
      const int nc = qt + 1;            // total causal chunks for this q-tile
      const int hs = (nc + 1) >> 1;     // half-split point
      const int c0 = piece ? hs : 0;
      const int c1 = piece ? nc : hs;
      bf16x8 Qf[16];
      {
        const bf16* qp = qb + (size_t)((qrow0 + w * 16 + lr) * 4 + b) * 1024 + h * 512 + q * 8;
#pragma unroll
        for (int kk = 0; kk < 16; kk++) Qf[kk] = *(const bf16x8*)(qp + kk * 32);
      }
      // stage K[c0] (harmless over-stage when c0==c1)
#pragma unroll
      for (int j = 0; j < 16; j++)
        gload16(krow0 + (size_t)((c0 * 32 + w * 16 + j) * 4) * 1024,
                &Ks[c0 & 1][(w * 16 + j) * 520]);
      __syncthreads();  // [B0] K[c0] visible
      const int myrow = qrow0 + w * 16 + q * 4;
      for (int t = c0; t <= c1; t++) {
        if (t < c1) {
          const int p = t & 1;
          const int kc = t * 32;
          // prefetch K[t+1] first — drained by this iter's end barrier
          if (t + 1 < c1) {
            const int kc2 = (t + 1) * 32;
#pragma unroll
            for (int j = 0; j < 16; j++)
              gload16(krow0 + (size_t)((kc2 + w * 16 + j) * 4) * 1024,
                      &Ks[1 - p][(w * 16 + j) * 520]);
          }
          const bool dead = kc > qrow0 + w * 16 + 15;
          float p0[4], p1[4];
          if (!dead) {
            f32x4 S0 = {}, S1 = {};
#pragma unroll
            for (int kk = 0; kk < 16; kk++) {
              const bf16x8 k0 = *(const bf16x8*)&Ks[p][lr * 520 + kk * 32 + q * 8];
              const bf16x8 k1 = *(const bf16x8*)&Ks[p][(16 + lr) * 520 + kk * 32 + q * 8];
              S0 = MFMA16x16x32(Qf[kk], k0, S0);
              S1 = MFMA16x16x32(Qf[kk], k1, S1);
            }
#pragma unroll
            for (int r = 0; r < 4; r++) {
              const int row = myrow + r;
              p0[r] = (kc + lr > row) ? 0.f : __expf(S0[r] * sc);
              p1[r] = (kc + 16 + lr > row) ? 0.f : __expf(S1[r] * sc);
            }
          } else {
#pragma unroll
            for (int r = 0; r < 4; r++) { p0[r] = 0.f; p1[r] = 0.f; }
          }
#pragma unroll
          for (int r = 0; r < 4; r++) {
            Ps[p][w][(q * 4 + r) * 40 + lr] = (bf16)p0[r];
            Ps[p][w][(q * 4 + r) * 40 + 16 + lr] = (bf16)p1[r];
          }
        }
        __syncthreads();  // [Bt] P[t] visible; K[t+1] landed; P[t-1] reads done
      }
    }
  } else {
    // ================= PV-waves =================
    const int pw = w - 2;  // 0..3, dims [128*pw, 128*pw+128)
    bf16x8 ones;
#pragma unroll
    for (int e = 0; e < 8; e++) ones[e] = (bf16)1.0f;
    const bf16* vbase = vtg + ((size_t)bh << 20) + (size_t)(pw * 128 + lr) * 2048 + q * 8;
    for (int piece = 0; piece < 2; ++piece) {
      const int qt = piece ? (63 - y) : y;
      const int qrow0 = qt * 32;
      const int nc = qt + 1;
      const int hs = (nc + 1) >> 1;
      const int c0 = piece ? hs : 0;
      const int c1 = piece ? nc : hs;
      f32x4 O[2][8] = {};
      f32x4 lac = {};
      __syncthreads();  // [B0]
      for (int t = c0; t <= c1; t++) {
        if (t > c0) {
          const int p = (t - 1) & 1;
          const int kc = (t - 1) * 32;
          bf16x8 pa[2];
#pragma unroll
          for (int rt = 0; rt < 2; rt++)
            pa[rt] = *(const bf16x8*)&Ps[p][rt][lr * 40 + q * 8];
          if (pw < 2) {
            // static select (avoid runtime-indexed register array -> scratch)
            const bf16x8 psel = pw == 0 ? pa[0] : pa[1];
            lac = MFMA16x16x32(psel, ones, lac);
          }
#pragma unroll
          for (int ct = 0; ct < 8; ct++) {
            const bf16x8 vf = *(const bf16x8*)(vbase + (size_t)(ct * 16) * 2048 + kc);
#pragma unroll
            for (int rt = 0; rt < 2; rt++)
              O[rt][ct] = MFMA16x16x32(pa[rt], vf, O[rt][ct]);
          }
        }
        __syncthreads();  // [Bt]
      }
      // ---- write partials: opart[half][bh][row 2048][dim 512] (= d_out) ----
      bf16* op = opart + (size_t)piece * (8u << 20) + (size_t)bh * (1u << 20);
#pragma unroll
      for (int rt = 0; rt < 2; rt++)
#pragma unroll
        for (int ct = 0; ct < 8; ct++)
#pragma unroll
          for (int r = 0; r < 4; r++)
            op[(size_t)(qrow0 + rt * 16 + q * 4 + r) * 512 + pw * 128 + ct * 16 + lr] =
                (bf16)O[rt][ct][r];
      if (lr == 0 && pw < 2) {
#pragma unroll
        for (int r = 0; r < 4; r++)
          lpart[piece * 16384 + bh * 2048 + qrow0 + pw * 16 + q * 4 + r] = lac[r];
      }
    }
  }
}

// ---------------- combine: ctx = (O0+O1)/(l0+l1), bf16 token-major ---------
__global__ __launch_bounds__(256) void attn_combine(
    const bf16* __restrict__ opart, const float* __restrict__ lpart,
    bf16* __restrict__ ctx)
{
  const int gid = blockIdx.x * 256 + threadIdx.x;
  const int bh = gid >> 17;
  const int rem = gid & 131071;
  const int row = rem >> 6;
  const int dc = (rem & 63) * 8;
  const size_t o = (size_t)bh * (1u << 20) + (size_t)row * 512 + dc;
  const bf16x8 a = *(const bf16x8*)(opart + o);
  const bf16x8 c = *(const bf16x8*)(opart + (size_t)(8u << 20) + o);
  const float inv = 1.0f /
      (lpart[bh * 2048 + row] + lpart[16384 + bh * 2048 + row]);
  bf16x8 ov;
#pragma unroll
  for (int e = 0; e < 8; e++) ov[e] = (bf16)(((float)a[e] + (float)c[e]) * inv);
  const int b = bh >> 1, h = bh & 1;
  *(bf16x8*)(ctx + (size_t)(row * 4 + b) * 1024 + h * 512 + dc) = ov;
}

// ---------------------------------------------------------------------------
extern "C" void kernel_launch(void* const* d_in, const int* in_sizes, int n_in,
                              void* d_out, int out_size, void* d_ws, size_t ws_size,
                              hipStream_t stream)
{
  (void)in_sizes; (void)n_in; (void)out_size; (void)ws_size;
  const float* x    = (const float*)d_in[0];
  const float* wn1  = (const float*)d_in[1];
  const float* wqkv = (const float*)d_in[2];
  const float* bqkv = (const float*)d_in[3];
  const float* wout = (const float*)d_in[4];
  const float* bout = (const float*)d_in[5];
  const float* wn2  = (const float*)d_in[6];
  const float* W1   = (const float*)d_in[7];
  const float* b1   = (const float*)d_in[8];
  const float* W2   = (const float*)d_in[9];
  const float* b2   = (const float*)d_in[10];
  float* out = (float*)d_out;

  char* ws = (char*)d_ws;
  const size_t Mi = 1u << 20;
  bf16* S0v = (bf16*)(ws);              // h -> vt -> m
  bf16* S1v = (bf16*)(ws + 16 * Mi);    // q -> ctx
  bf16* S2v = (bf16*)(ws + 32 * Mi);    // k -> g (lower half)
  bf16* S3v = (bf16*)(ws + 48 * Mi);    // vtmp -> l -> g (upper half)
  bf16* wqb = (bf16*)(ws + 64 * Mi);
  bf16* wob = (bf16*)(ws + 70 * Mi);
  bf16* w1b = (bf16*)(ws + 72 * Mi);
  bf16* w2b = (bf16*)(ws + 76 * Mi);
  const int M = 8192;

  wcvt4<<<8192, 256, 0, stream>>>(wqkv, wqb, wout, wob, W1, w1b, W2, w2b);
  rmsnorm_kernel<<<8192, 256, 0, stream>>>(x, wn1, S0v);
  gemm_bt2<EPI_QKV><<<64 * 24, 256, 0, stream>>>(
      S0v, wqb, bqkv, nullptr, nullptr, S1v, S2v, S3v, M, 3072, 1024);
  vtrans_kernel<<<dim3(32, 8, 8), 256, 0, stream>>>(S3v, S0v);
  attn_kernel<<<dim3(8, 64), 384, 0, stream>>>(
      S1v, S2v, S0v, (bf16*)d_out, (float*)S3v);
  attn_combine<<<4096, 256, 0, stream>>>((const bf16*)d_out, (const float*)S3v, S1v);
  gemm_bt2<EPI_RES><<<64 * 8, 256, 0, stream>>>(
      S1v, wob, bout, x, out, nullptr, nullptr, nullptr, M, 1024, 1024);
  rmsnorm_kernel<<<8192, 256, 0, stream>>>(out, wn2, S0v);
  gemm_bt2<EPI_GELU><<<64 * 16, 256, 0, stream>>>(
      S0v, w1b, b1, nullptr, nullptr, S2v, nullptr, nullptr, M, 2048, 1024);
  gemm_bt2<EPI_RES><<<64 * 8, 256, 0, stream>>>(
      S2v, w2b, b2, out, out, nullptr, nullptr, nullptr, M, 1024, 2048);
}

// Round 9
// 418.387 us; speedup vs baseline: 1.1244x; 1.1244x over previous
//
#include <hip/hip_runtime.h>

// ---------------------------------------------------------------------------
// TransformerBlock on MI355X (gfx950) — round 13.
// Token-major: t = s*B + b, x is (8192, 1024).
// GEMM: T3 minimum 2-phase (round-11 state, measured ~73us QKV; neutral vs
// two-barrier — kept).
// Attention v9: v7 shape (768 thr, 12 waves, grid 8x32, 1 blk/CU) with
// 64-KEY CHUNKS — barriers/block 35 -> ~19, per-chunk work doubled so the
// per-barrier drain amortizes. v8 (2 blk/CU attempt) REVERTED: occupancy
// fell to 16% (2nd block never resident), dur 125us.
// Ks 2x[64x520] (133KB) + Ps 2x4x[16x72] (18.4KB) = 151.5KB LDS.
// Tile qt: nc=qt+1 chunks; block y: piece0=(qt=y, [0,ceil(nc/2))),
// piece1=(qt=31-y, [ceil(nc/2), nc)); empty pieces write zero partials.
// Same opart/lpart/attn_combine contract as v7.
// ws slots (MiB): S0[0,16) h/vt/m; S1[16,32) q/ctx; S2[32,48) k/g.lo;
// S3[48,64) vtmp/l/g.hi; [64,80) bf16 weights. d_out = attn partial scratch.
// ---------------------------------------------------------------------------

typedef __bf16 bf16;
typedef bf16 bf16x8 __attribute__((ext_vector_type(8)));
typedef bf16 bf16x4 __attribute__((ext_vector_type(4)));
typedef float f32x4 __attribute__((ext_vector_type(4)));

#define MFMA16x16x32(A, B, C) __builtin_amdgcn_mfma_f32_16x16x32_bf16(A, B, C, 0, 0, 0)

__device__ __forceinline__ void gload16(const void* g, void* l) {
  __builtin_amdgcn_global_load_lds(
      (const __attribute__((address_space(1))) void*)g,
      (__attribute__((address_space(3))) void*)l, 16, 0, 0);
}

// ---------------- f32 -> bf16 weight conversion (all 4 weights) ------------
__global__ __launch_bounds__(256) void wcvt4(
    const float* __restrict__ s0, bf16* __restrict__ d0,
    const float* __restrict__ s1, bf16* __restrict__ d1,
    const float* __restrict__ s2, bf16* __restrict__ d2,
    const float* __restrict__ s3, bf16* __restrict__ d3)
{
  const int gid = blockIdx.x * 256 + threadIdx.x;  // quad index, 2097152 total
  const float* s; bf16* d; int off;
  if (gid < 786432)       { s = s0; d = d0; off = gid; }
  else if (gid < 1048576) { s = s1; d = d1; off = gid - 786432; }
  else if (gid < 1572864) { s = s2; d = d2; off = gid - 1048576; }
  else                    { s = s3; d = d3; off = gid - 1572864; }
  const int i = off * 4;
  const float4 v = *(const float4*)(s + i);
  bf16x4 o;
  o[0] = (bf16)v.x; o[1] = (bf16)v.y; o[2] = (bf16)v.z; o[3] = (bf16)v.w;
  *(bf16x4*)(d + i) = o;
}

// ---------------- RMSNorm: (8192 x 1024) f32 -> bf16 -----------------------
__global__ __launch_bounds__(256) void rmsnorm_kernel(
    const float* __restrict__ x, const float* __restrict__ w, bf16* __restrict__ out)
{
  const int row = blockIdx.x;
  const int tid = threadIdx.x;
  const float4 v = *(const float4*)(x + (size_t)row * 1024 + tid * 4);
  float ss = v.x * v.x + v.y * v.y + v.z * v.z + v.w * v.w;
#pragma unroll
  for (int off = 1; off < 64; off <<= 1) ss += __shfl_xor(ss, off, 64);
  __shared__ float red[4];
  if ((tid & 63) == 0) red[tid >> 6] = ss;
  __syncthreads();
  const float tot = red[0] + red[1] + red[2] + red[3];
  const float inv = rsqrtf(tot * (1.0f / 1024.0f) + 1e-8f);
  const float4 g = *(const float4*)(w + tid * 4);
  bf16x4 o;
  o[0] = (bf16)(v.x * g.x * inv);
  o[1] = (bf16)(v.y * g.y * inv);
  o[2] = (bf16)(v.z * g.z * inv);
  o[3] = (bf16)(v.w * g.w * inv);
  *(bf16x4*)(out + (size_t)row * 1024 + tid * 4) = o;
}

// ---------------- GEMM: C = A * W^T + bias, 128x128, 2-phase ---------------
enum { EPI_BF16 = 0, EPI_RES = 1, EPI_GELU = 2, EPI_QKV = 3 };

template <int EPI>
__global__ __launch_bounds__(256, 3) void gemm_bt2(
    const bf16* __restrict__ A,   // M x K
    const bf16* __restrict__ B,   // N x K
    const float* __restrict__ bias,
    const float* res,             // may alias outF
    float* outF, bf16* outQ, bf16* outK, bf16* outV,
    int M, int N, int K)
{
  __shared__ bf16 lds[2][8192];  // 2 buffers x (As 4096 + Bs 4096) = 32 KB
  const int tid = threadIdx.x;
  // super-rows of 16 bm: concurrent blocks share a 4 MB A-slice (L2-resident)
  const int Nb = N >> 7;
  const int lin = blockIdx.x;
  const int sup = lin / (Nb << 4);
  const int rem = lin - sup * (Nb << 4);
  const int bm = (sup << 4) + (rem & 15);
  const int bn = rem >> 4;
  const int w = tid >> 6, lane = tid & 63;
  const int q = lane >> 4, lr = lane & 15;
  const int wr = (w >> 1) * 64, wc = (w & 1) * 64;
  f32x4 acc[4][4] = {};
  const int srow = lane >> 2;
  const int gch = ((lane & 3) - ((lane >> 3) & 3)) & 3;
  const bf16* Ab = A + (size_t)(bm * 128) * K;
  const bf16* Bb = B + (size_t)(bn * 128) * K;
  const int sw = ((q + (lr >> 1)) & 3) * 16;
  const int NK = K >> 5;

  // stage one BK=32 K-tile into buffer `dst` (4 gloads/thread: 2xA + 2xB)
#define STAGE(dst, k0)                                                        \
  {                                                                           \
    bf16* De = (dst);                                                         \
    _Pragma("unroll")                                                         \
    for (int c = 0; c < 2; c++) {                                             \
      const int r = (w * 2 + c) * 16 + srow;                                  \
      gload16(Ab + (size_t)r * K + (k0) + gch * 8, De + (w * 2 + c) * 512);   \
      gload16(Bb + (size_t)r * K + (k0) + gch * 8, De + 4096 + (w * 2 + c) * 512); \
    }                                                                         \
  }

  STAGE(&lds[0][0], 0);
  __syncthreads();  // tile 0 visible
#pragma unroll 1
  for (int u = 0; u < NK; ++u) {
    bf16* cur = &lds[u & 1][0];
    bf16* nxt = &lds[(u + 1) & 1][0];
    // T3 minimum 2-phase: issue next-tile stage FIRST, compute under it.
    if (u + 1 < NK) STAGE(nxt, (u + 1) * 32);
    const char* As = (const char*)cur;
    const char* Bs = (const char*)(cur + 4096);
    bf16x8 af[4], bfr[4];
#pragma unroll
    for (int mt = 0; mt < 4; mt++)
      af[mt] = *(const bf16x8*)(As + (wr + mt * 16 + lr) * 64 + sw);
#pragma unroll
    for (int nt = 0; nt < 4; nt++)
      bfr[nt] = *(const bf16x8*)(Bs + (wc + nt * 16 + lr) * 64 + sw);
#pragma unroll
    for (int mt = 0; mt < 4; mt++)
#pragma unroll
      for (int nt = 0; nt < 4; nt++)
        acc[mt][nt] = MFMA16x16x32(af[mt], bfr[nt], acc[mt][nt]);
    __syncthreads();
  }
#undef STAGE

  const int gm0 = bm * 128 + wr + q * 4;
  const int gn0 = bn * 128 + wc + lr;
  bf16* outs = nullptr;
  if constexpr (EPI == EPI_QKV) {
    const int reg = (bn * 128) >> 10;
    outs = reg == 0 ? outQ : (reg == 1 ? outK : outV);
  } else {
    outs = outQ;
  }
#pragma unroll
  for (int nt = 0; nt < 4; nt++) {
    const int gn = gn0 + nt * 16;
    const float bv = bias[gn];
#pragma unroll
    for (int mt = 0; mt < 4; mt++) {
#pragma unroll
      for (int r = 0; r < 4; r++) {
        float v = acc[mt][nt][r] + bv;
        const int gm = gm0 + mt * 16 + r;
        if constexpr (EPI == EPI_GELU) {
          v = 0.5f * v * (1.0f + erff(v * 0.70710678118654752f));
          outs[(size_t)gm * N + gn] = (bf16)v;
        } else if constexpr (EPI == EPI_BF16) {
          outs[(size_t)gm * N + gn] = (bf16)v;
        } else if constexpr (EPI == EPI_QKV) {
          outs[(size_t)gm * 1024 + (gn & 1023)] = (bf16)v;
        } else {
          const size_t idx = (size_t)gm * N + gn;
          outF[idx] = v + res[idx];
        }
      }
    }
  }
}

// ---------------- V transpose: vtmp (t,n) -> vt[bh][dim][key] --------------
__global__ __launch_bounds__(256) void vtrans_kernel(
    const bf16* __restrict__ vtmp, bf16* __restrict__ vt)
{
  __shared__ bf16 tile[64 * 72];
  const int kt = blockIdx.x;
  const int dt = blockIdx.y;
  const int bh = blockIdx.z;
  const int b = bh >> 1, h = bh & 1;
  const int tid = threadIdx.x;
#pragma unroll
  for (int it = 0; it < 2; it++) {
    const int key = it * 32 + (tid >> 3);
    const int dc = (tid & 7) * 8;
    const bf16x8 v = *(const bf16x8*)(vtmp +
        (size_t)((kt * 64 + key) * 4 + b) * 1024 + h * 512 + dt * 64 + dc);
    *(bf16x8*)&tile[key * 72 + dc] = v;
  }
  __syncthreads();
#pragma unroll
  for (int it = 0; it < 2; it++) {
    const int dim = it * 32 + (tid >> 3);
    const int kc = (tid & 7) * 8;
    bf16x8 o;
#pragma unroll
    for (int j = 0; j < 8; j++) o[j] = tile[(kc + j) * 72 + dim];
    *(bf16x8*)(vt + (size_t)bh * (1u << 20) +
               (size_t)(dt * 64 + dim) * 2048 + kt * 64 + kc) = o;
  }
}

// ---------------- Attention v9: 12 waves, 64-key chunks --------------------
// 768 threads: waves 0-3 = S-waves (rows [16w,16w+16) of a 64-row Q-tile),
// waves 4-11 = PV (dims [64(w-4),+64), O[4][4]=64 AGPR). Grid (8,32), 1
// blk/CU. Chunk = 64 keys: barriers/block ~19 (vs 35 at 32-key), per-chunk
// work doubled so per-barrier drain amortizes. Double-buffered Ks/Ps; S
// stages K[t+1], computes P[t]; PV consumes P[t-1]; one barrier per chunk.
__global__ __launch_bounds__(768, 3) void attn_kernel(
    const bf16* __restrict__ qb, const bf16* __restrict__ kb,
    const bf16* __restrict__ vtg, bf16* __restrict__ opart,
    float* __restrict__ lpart)
{
  __shared__ bf16 Ks[2][64 * 520];   // 2 x 66560 B
  __shared__ bf16 Ps[2][4][16 * 72]; // 2 x  9216 B  (151552 total)
  const int bh = blockIdx.x;          // 0..7 -> XCD affinity
  const int y = blockIdx.y;           // 0..31
  const int b = bh >> 1, h = bh & 1;
  const int tid = threadIdx.x;
  const int w = tid >> 6, lane = tid & 63;
  const int q = lane >> 4, lr = lane & 15;
  const float sc = 0.044194173824159216f;  // 1/sqrt(512)

  if (w < 4) {
    // ================= S-waves =================
    const bf16* krow0 = kb + (size_t)b * 1024 + h * 512 + lane * 8;  // per-lane 16B
    for (int piece = 0; piece < 2; ++piece) {
      const int qt = piece ? (31 - y) : y;
      const int qrow0 = qt * 64;
      const int nc = qt + 1;            // 64-key chunks for this q-tile
      const int hs = (nc + 1) >> 1;
      const int c0 = piece ? hs : 0;
      const int c1 = piece ? nc : hs;
      bf16x8 Qf[16];
      {
        const bf16* qp = qb + (size_t)((qrow0 + w * 16 + lr) * 4 + b) * 1024 + h * 512 + q * 8;
#pragma unroll
        for (int kk = 0; kk < 16; kk++) Qf[kk] = *(const bf16x8*)(qp + kk * 32);
      }
      // stage K[c0] (rows w*16..+15; when c0==c1 this is a harmless in-range
      // over-stage: c0==c1 only for nc==1 -> chunk 1 = keys 64..127)
#pragma unroll
      for (int j = 0; j < 16; j++)
        gload16(krow0 + (size_t)((c0 * 64 + w * 16 + j) * 4) * 1024,
                &Ks[c0 & 1][(w * 16 + j) * 520]);
      __syncthreads();  // [B0] K[c0] visible
      const int myrow = qrow0 + w * 16 + q * 4;
      for (int t = c0; t <= c1; t++) {
        if (t < c1) {
          const int p = t & 1;
          const int kc = t * 64;
          // prefetch K[t+1] first — drained by this iter's end barrier
          if (t + 1 < c1) {
            const int kc2 = (t + 1) * 64;
#pragma unroll
            for (int j = 0; j < 16; j++)
              gload16(krow0 + (size_t)((kc2 + w * 16 + j) * 4) * 1024,
                      &Ks[1 - p][(w * 16 + j) * 520]);
          }
          f32x4 S0 = {}, S1 = {}, S2 = {}, S3 = {};
#pragma unroll
          for (int kk = 0; kk < 16; kk++) {
            const bf16x8 k0 = *(const bf16x8*)&Ks[p][lr * 520 + kk * 32 + q * 8];
            const bf16x8 k1 = *(const bf16x8*)&Ks[p][(16 + lr) * 520 + kk * 32 + q * 8];
            const bf16x8 k2 = *(const bf16x8*)&Ks[p][(32 + lr) * 520 + kk * 32 + q * 8];
            const bf16x8 k3 = *(const bf16x8*)&Ks[p][(48 + lr) * 520 + kk * 32 + q * 8];
            S0 = MFMA16x16x32(Qf[kk], k0, S0);
            S1 = MFMA16x16x32(Qf[kk], k1, S1);
            S2 = MFMA16x16x32(Qf[kk], k2, S2);
            S3 = MFMA16x16x32(Qf[kk], k3, S3);
          }
#pragma unroll
          for (int r = 0; r < 4; r++) {
            const int row = myrow + r;
            const float p0 = (kc + lr > row) ? 0.f : __expf(S0[r] * sc);
            const float p1 = (kc + 16 + lr > row) ? 0.f : __expf(S1[r] * sc);
            const float p2 = (kc + 32 + lr > row) ? 0.f : __expf(S2[r] * sc);
            const float p3 = (kc + 48 + lr > row) ? 0.f : __expf(S3[r] * sc);
            bf16* pr = &Ps[p][w][(q * 4 + r) * 72];
            pr[lr] = (bf16)p0;
            pr[16 + lr] = (bf16)p1;
            pr[32 + lr] = (bf16)p2;
            pr[48 + lr] = (bf16)p3;
          }
        }
        __syncthreads();  // [Bt] P[t] visible; K[t+1] landed; P[t-1] reads done
      }
    }
  } else {
    // ================= PV-waves =================
    const int pw = w - 4;  // 0..7, dims [64*pw, 64*pw+64)
    bf16x8 ones;
#pragma unroll
    for (int e = 0; e < 8; e++) ones[e] = (bf16)1.0f;
    const bf16* vbase = vtg + ((size_t)bh << 20) + (size_t)(pw * 64 + lr) * 2048 + q * 8;
    for (int piece = 0; piece < 2; ++piece) {
      const int qt = piece ? (31 - y) : y;
      const int qrow0 = qt * 64;
      const int nc = qt + 1;
      const int hs = (nc + 1) >> 1;
      const int c0 = piece ? hs : 0;
      const int c1 = piece ? nc : hs;
      f32x4 O[4][4] = {};
      f32x4 lac = {};
      __syncthreads();  // [B0]
      for (int t = c0; t <= c1; t++) {
        if (t > c0) {
          const int p = (t - 1) & 1;
          const int kc = (t - 1) * 64;
#pragma unroll
          for (int s = 0; s < 2; s++) {
            bf16x8 pa[4];
#pragma unroll
            for (int rt = 0; rt < 4; rt++)
              pa[rt] = *(const bf16x8*)&Ps[p][rt][lr * 72 + s * 32 + q * 8];
            if (pw < 4) {
              // static select (avoid runtime-indexed register array -> scratch)
              const bf16x8 psel = pw == 0 ? pa[0] : (pw == 1 ? pa[1] : (pw == 2 ? pa[2] : pa[3]));
              lac = MFMA16x16x32(psel, ones, lac);
            }
#pragma unroll
            for (int ct = 0; ct < 4; ct++) {
              const bf16x8 vf = *(const bf16x8*)(vbase + (size_t)(ct * 16) * 2048 + kc + s * 32);
#pragma unroll
              for (int rt = 0; rt < 4; rt++)
                O[rt][ct] = MFMA16x16x32(pa[rt], vf, O[rt][ct]);
            }
          }
        }
        __syncthreads();  // [Bt]
      }
      // ---- write partials: opart[half][bh][row 2048][dim 512] (= d_out) ----
      bf16* op = opart + (size_t)piece * (8u << 20) + (size_t)bh * (1u << 20);
#pragma unroll
      for (int rt = 0; rt < 4; rt++)
#pragma unroll
        for (int ct = 0; ct < 4; ct++)
#pragma unroll
          for (int r = 0; r < 4; r++)
            op[(size_t)(qrow0 + rt * 16 + q * 4 + r) * 512 + pw * 64 + ct * 16 + lr] =
                (bf16)O[rt][ct][r];
      if (lr == 0 && pw < 4) {
#pragma unroll
        for (int r = 0; r < 4; r++)
          lpart[piece * 16384 + bh * 2048 + qrow0 + pw * 16 + q * 4 + r] = lac[r];
      }
    }
  }
}

// ---------------- combine: ctx = (O0+O1)/(l0+l1), bf16 token-major ---------
__global__ __launch_bounds__(256) void attn_combine(
    const bf16* __restrict__ opart, const float* __restrict__ lpart,
    bf16* __restrict__ ctx)
{
  const int gid = blockIdx.x * 256 + threadIdx.x;
  const int bh = gid >> 17;
  const int rem = gid & 131071;
  const int row = rem >> 6;
  const int dc = (rem & 63) * 8;
  const size_t o = (size_t)bh * (1u << 20) + (size_t)row * 512 + dc;
  const bf16x8 a = *(const bf16x8*)(opart + o);
  const bf16x8 c = *(const bf16x8*)(opart + (size_t)(8u << 20) + o);
  const float inv = 1.0f /
      (lpart[bh * 2048 + row] + lpart[16384 + bh * 2048 + row]);
  bf16x8 ov;
#pragma unroll
  for (int e = 0; e < 8; e++) ov[e] = (bf16)(((float)a[e] + (float)c[e]) * inv);
  const int b = bh >> 1, h = bh & 1;
  *(bf16x8*)(ctx + (size_t)(row * 4 + b) * 1024 + h * 512 + dc) = ov;
}

// ---------------------------------------------------------------------------
extern "C" void kernel_launch(void* const* d_in, const int* in_sizes, int n_in,
                              void* d_out, int out_size, void* d_ws, size_t ws_size,
                              hipStream_t stream)
{
  (void)in_sizes; (void)n_in; (void)out_size; (void)ws_size;
  const float* x    = (const float*)d_in[0];
  const float* wn1  = (const float*)d_in[1];
  const float* wqkv = (const float*)d_in[2];
  const float* bqkv = (const float*)d_in[3];
  const float* wout = (const float*)d_in[4];
  const float* bout = (const float*)d_in[5];
  const float* wn2  = (const float*)d_in[6];
  const float* W1   = (const float*)d_in[7];
  const float* b1   = (const float*)d_in[8];
  const float* W2   = (const float*)d_in[9];
  const float* b2   = (const float*)d_in[10];
  float* out = (float*)d_out;

  char* ws = (char*)d_ws;
  const size_t Mi = 1u << 20;
  bf16* S0v = (bf16*)(ws);              // h -> vt -> m
  bf16* S1v = (bf16*)(ws + 16 * Mi);    // q -> ctx
  bf16* S2v = (bf16*)(ws + 32 * Mi);    // k -> g (lower half)
  bf16* S3v = (bf16*)(ws + 48 * Mi);    // vtmp -> l -> g (upper half)
  bf16* wqb = (bf16*)(ws + 64 * Mi);
  bf16* wob = (bf16*)(ws + 70 * Mi);
  bf16* w1b = (bf16*)(ws + 72 * Mi);
  bf16* w2b = (bf16*)(ws + 76 * Mi);
  const int M = 8192;

  wcvt4<<<8192, 256, 0, stream>>>(wqkv, wqb, wout, wob, W1, w1b, W2, w2b);
  rmsnorm_kernel<<<8192, 256, 0, stream>>>(x, wn1, S0v);
  gemm_bt2<EPI_QKV><<<64 * 24, 256, 0, stream>>>(
      S0v, wqb, bqkv, nullptr, nullptr, S1v, S2v, S3v, M, 3072, 1024);
  vtrans_kernel<<<dim3(32, 8, 8), 256, 0, stream>>>(S3v, S0v);
  attn_kernel<<<dim3(8, 32), 768, 0, stream>>>(
      S1v, S2v, S0v, (bf16*)d_out, (float*)S3v);
  attn_combine<<<4096, 256, 0, stream>>>((const bf16*)d_out, (const float*)S3v, S1v);
  gemm_bt2<EPI_RES><<<64 * 8, 256, 0, stream>>>(
      S1v, wob, bout, x, out, nullptr, nullptr, nullptr, M, 1024, 1024);
  rmsnorm_kernel<<<8192, 256, 0, stream>>>(out, wn2, S0v);
  gemm_bt2<EPI_GELU><<<64 * 16, 256, 0, stream>>>(
      S0v, w1b, b1, nullptr, nullptr, S2v, nullptr, nullptr, M, 2048, 1024);
  gemm_bt2<EPI_RES><<<64 * 8, 256, 0, stream>>>(
      S2v, w2b, b2, out, out, nullptr, nullptr, nullptr, M, 1024, 2048);
}

// Round 10
// 410.149 us; speedup vs baseline: 1.1470x; 1.0201x over previous
//
#include <hip/hip_runtime.h>

// ---------------------------------------------------------------------------
// TransformerBlock on MI355X (gfx950) — round 14.
// Token-major: t = s*B + b, x is (8192, 1024).
// GEMM: T3 minimum 2-phase, __launch_bounds__(256,4) — ONE change vs r13:
// 3 -> 4 blocks/CU (regs 56V+64A=120<=128/wave at 4 w/SIMD; LDS 4x32=128KB
// <=160). Mechanism: m114 cross-block overlap hides the per-K-tile barrier
// drain; a 4th resident block adds an interleave partner. 3 schedules tied
// at ~72us @ 3 blk/CU -> residency is the un-pulled lever.
// Attention v9 (64-key chunks, 12 waves) unchanged from r13.
// ws slots (MiB): S0[0,16) h/vt/m; S1[16,32) q/ctx; S2[32,48) k/g.lo;
// S3[48,64) vtmp/l/g.hi; [64,80) bf16 weights. d_out = attn partial scratch.
// ---------------------------------------------------------------------------

typedef __bf16 bf16;
typedef bf16 bf16x8 __attribute__((ext_vector_type(8)));
typedef bf16 bf16x4 __attribute__((ext_vector_type(4)));
typedef float f32x4 __attribute__((ext_vector_type(4)));

#define MFMA16x16x32(A, B, C) __builtin_amdgcn_mfma_f32_16x16x32_bf16(A, B, C, 0, 0, 0)

__device__ __forceinline__ void gload16(const void* g, void* l) {
  __builtin_amdgcn_global_load_lds(
      (const __attribute__((address_space(1))) void*)g,
      (__attribute__((address_space(3))) void*)l, 16, 0, 0);
}

// ---------------- f32 -> bf16 weight conversion (all 4 weights) ------------
__global__ __launch_bounds__(256) void wcvt4(
    const float* __restrict__ s0, bf16* __restrict__ d0,
    const float* __restrict__ s1, bf16* __restrict__ d1,
    const float* __restrict__ s2, bf16* __restrict__ d2,
    const float* __restrict__ s3, bf16* __restrict__ d3)
{
  const int gid = blockIdx.x * 256 + threadIdx.x;  // quad index, 2097152 total
  const float* s; bf16* d; int off;
  if (gid < 786432)       { s = s0; d = d0; off = gid; }
  else if (gid < 1048576) { s = s1; d = d1; off = gid - 786432; }
  else if (gid < 1572864) { s = s2; d = d2; off = gid - 1048576; }
  else                    { s = s3; d = d3; off = gid - 1572864; }
  const int i = off * 4;
  const float4 v = *(const float4*)(s + i);
  bf16x4 o;
  o[0] = (bf16)v.x; o[1] = (bf16)v.y; o[2] = (bf16)v.z; o[3] = (bf16)v.w;
  *(bf16x4*)(d + i) = o;
}

// ---------------- RMSNorm: (8192 x 1024) f32 -> bf16 -----------------------
__global__ __launch_bounds__(256) void rmsnorm_kernel(
    const float* __restrict__ x, const float* __restrict__ w, bf16* __restrict__ out)
{
  const int row = blockIdx.x;
  const int tid = threadIdx.x;
  const float4 v = *(const float4*)(x + (size_t)row * 1024 + tid * 4);
  float ss = v.x * v.x + v.y * v.y + v.z * v.z + v.w * v.w;
#pragma unroll
  for (int off = 1; off < 64; off <<= 1) ss += __shfl_xor(ss, off, 64);
  __shared__ float red[4];
  if ((tid & 63) == 0) red[tid >> 6] = ss;
  __syncthreads();
  const float tot = red[0] + red[1] + red[2] + red[3];
  const float inv = rsqrtf(tot * (1.0f / 1024.0f) + 1e-8f);
  const float4 g = *(const float4*)(w + tid * 4);
  bf16x4 o;
  o[0] = (bf16)(v.x * g.x * inv);
  o[1] = (bf16)(v.y * g.y * inv);
  o[2] = (bf16)(v.z * g.z * inv);
  o[3] = (bf16)(v.w * g.w * inv);
  *(bf16x4*)(out + (size_t)row * 1024 + tid * 4) = o;
}

// ---------------- GEMM: C = A * W^T + bias, 128x128, 2-phase ---------------
enum { EPI_BF16 = 0, EPI_RES = 1, EPI_GELU = 2, EPI_QKV = 3 };

template <int EPI>
__global__ __launch_bounds__(256, 4) void gemm_bt2(
    const bf16* __restrict__ A,   // M x K
    const bf16* __restrict__ B,   // N x K
    const float* __restrict__ bias,
    const float* res,             // may alias outF
    float* outF, bf16* outQ, bf16* outK, bf16* outV,
    int M, int N, int K)
{
  __shared__ bf16 lds[2][8192];  // 2 buffers x (As 4096 + Bs 4096) = 32 KB
  const int tid = threadIdx.x;
  // super-rows of 16 bm: concurrent blocks share a 4 MB A-slice (L2-resident)
  const int Nb = N >> 7;
  const int lin = blockIdx.x;
  const int sup = lin / (Nb << 4);
  const int rem = lin - sup * (Nb << 4);
  const int bm = (sup << 4) + (rem & 15);
  const int bn = rem >> 4;
  const int w = tid >> 6, lane = tid & 63;
  const int q = lane >> 4, lr = lane & 15;
  const int wr = (w >> 1) * 64, wc = (w & 1) * 64;
  f32x4 acc[4][4] = {};
  const int srow = lane >> 2;
  const int gch = ((lane & 3) - ((lane >> 3) & 3)) & 3;
  const bf16* Ab = A + (size_t)(bm * 128) * K;
  const bf16* Bb = B + (size_t)(bn * 128) * K;
  const int sw = ((q + (lr >> 1)) & 3) * 16;
  const int NK = K >> 5;

  // stage one BK=32 K-tile into buffer `dst` (4 gloads/thread: 2xA + 2xB)
#define STAGE(dst, k0)                                                        \
  {                                                                           \
    bf16* De = (dst);                                                         \
    _Pragma("unroll")                                                         \
    for (int c = 0; c < 2; c++) {                                             \
      const int r = (w * 2 + c) * 16 + srow;                                  \
      gload16(Ab + (size_t)r * K + (k0) + gch * 8, De + (w * 2 + c) * 512);   \
      gload16(Bb + (size_t)r * K + (k0) + gch * 8, De + 4096 + (w * 2 + c) * 512); \
    }                                                                         \
  }

  STAGE(&lds[0][0], 0);
  __syncthreads();  // tile 0 visible
#pragma unroll 1
  for (int u = 0; u < NK; ++u) {
    bf16* cur = &lds[u & 1][0];
    bf16* nxt = &lds[(u + 1) & 1][0];
    // T3 minimum 2-phase: issue next-tile stage FIRST, compute under it.
    if (u + 1 < NK) STAGE(nxt, (u + 1) * 32);
    const char* As = (const char*)cur;
    const char* Bs = (const char*)(cur + 4096);
    bf16x8 af[4], bfr[4];
#pragma unroll
    for (int mt = 0; mt < 4; mt++)
      af[mt] = *(const bf16x8*)(As + (wr + mt * 16 + lr) * 64 + sw);
#pragma unroll
    for (int nt = 0; nt < 4; nt++)
      bfr[nt] = *(const bf16x8*)(Bs + (wc + nt * 16 + lr) * 64 + sw);
#pragma unroll
    for (int mt = 0; mt < 4; mt++)
#pragma unroll
      for (int nt = 0; nt < 4; nt++)
        acc[mt][nt] = MFMA16x16x32(af[mt], bfr[nt], acc[mt][nt]);
    __syncthreads();
  }
#undef STAGE

  const int gm0 = bm * 128 + wr + q * 4;
  const int gn0 = bn * 128 + wc + lr;
  bf16* outs = nullptr;
  if constexpr (EPI == EPI_QKV) {
    const int reg = (bn * 128) >> 10;
    outs = reg == 0 ? outQ : (reg == 1 ? outK : outV);
  } else {
    outs = outQ;
  }
#pragma unroll
  for (int nt = 0; nt < 4; nt++) {
    const int gn = gn0 + nt * 16;
    const float bv = bias[gn];
#pragma unroll
    for (int mt = 0; mt < 4; mt++) {
#pragma unroll
      for (int r = 0; r < 4; r++) {
        float v = acc[mt][nt][r] + bv;
        const int gm = gm0 + mt * 16 + r;
        if constexpr (EPI == EPI_GELU) {
          v = 0.5f * v * (1.0f + erff(v * 0.70710678118654752f));
          outs[(size_t)gm * N + gn] = (bf16)v;
        } else if constexpr (EPI == EPI_BF16) {
          outs[(size_t)gm * N + gn] = (bf16)v;
        } else if constexpr (EPI == EPI_QKV) {
          outs[(size_t)gm * 1024 + (gn & 1023)] = (bf16)v;
        } else {
          const size_t idx = (size_t)gm * N + gn;
          outF[idx] = v + res[idx];
        }
      }
    }
  }
}

// ---------------- V transpose: vtmp (t,n) -> vt[bh][dim][key] --------------
__global__ __launch_bounds__(256) void vtrans_kernel(
    const bf16* __restrict__ vtmp, bf16* __restrict__ vt)
{
  __shared__ bf16 tile[64 * 72];
  const int kt = blockIdx.x;
  const int dt = blockIdx.y;
  const int bh = blockIdx.z;
  const int b = bh >> 1, h = bh & 1;
  const int tid = threadIdx.x;
#pragma unroll
  for (int it = 0; it < 2; it++) {
    const int key = it * 32 + (tid >> 3);
    const int dc = (tid & 7) * 8;
    const bf16x8 v = *(const bf16x8*)(vtmp +
        (size_t)((kt * 64 + key) * 4 + b) * 1024 + h * 512 + dt * 64 + dc);
    *(bf16x8*)&tile[key * 72 + dc] = v;
  }
  __syncthreads();
#pragma unroll
  for (int it = 0; it < 2; it++) {
    const int dim = it * 32 + (tid >> 3);
    const int kc = (tid & 7) * 8;
    bf16x8 o;
#pragma unroll
    for (int j = 0; j < 8; j++) o[j] = tile[(kc + j) * 72 + dim];
    *(bf16x8*)(vt + (size_t)bh * (1u << 20) +
               (size_t)(dt * 64 + dim) * 2048 + kt * 64 + kc) = o;
  }
}

// ---------------- Attention v9: 12 waves, 64-key chunks --------------------
__global__ __launch_bounds__(768, 3) void attn_kernel(
    const bf16* __restrict__ qb, const bf16* __restrict__ kb,
    const bf16* __restrict__ vtg, bf16* __restrict__ opart,
    float* __restrict__ lpart)
{
  __shared__ bf16 Ks[2][64 * 520];   // 2 x 66560 B
  __shared__ bf16 Ps[2][4][16 * 72]; // 2 x  9216 B  (151552 total)
  const int bh = blockIdx.x;          // 0..7 -> XCD affinity
  const int y = blockIdx.y;           // 0..31
  const int b = bh >> 1, h = bh & 1;
  const int tid = threadIdx.x;
  const int w = tid >> 6, lane = tid & 63;
  const int q = lane >> 4, lr = lane & 15;
  const float sc = 0.044194173824159216f;  // 1/sqrt(512)

  if (w < 4) {
    // ================= S-waves =================
    const bf16* krow0 = kb + (size_t)b * 1024 + h * 512 + lane * 8;  // per-lane 16B
    for (int piece = 0; piece < 2; ++piece) {
      const int qt = piece ? (31 - y) : y;
      const int qrow0 = qt * 64;
      const int nc = qt + 1;            // 64-key chunks for this q-tile
      const int hs = (nc + 1) >> 1;
      const int c0 = piece ? hs : 0;
      const int c1 = piece ? nc : hs;
      bf16x8 Qf[16];
      {
        const bf16* qp = qb + (size_t)((qrow0 + w * 16 + lr) * 4 + b) * 1024 + h * 512 + q * 8;
#pragma unroll
        for (int kk = 0; kk < 16; kk++) Qf[kk] = *(const bf16x8*)(qp + kk * 32);
      }
      // stage K[c0] (rows w*16..+15; when c0==c1 this is a harmless in-range
      // over-stage: c0==c1 only for nc==1 -> chunk 1 = keys 64..127)
#pragma unroll
      for (int j = 0; j < 16; j++)
        gload16(krow0 + (size_t)((c0 * 64 + w * 16 + j) * 4) * 1024,
                &Ks[c0 & 1][(w * 16 + j) * 520]);
      __syncthreads();  // [B0] K[c0] visible
      const int myrow = qrow0 + w * 16 + q * 4;
      for (int t = c0; t <= c1; t++) {
        if (t < c1) {
          const int p = t & 1;
          const int kc = t * 64;
          // prefetch K[t+1] first — drained by this iter's end barrier
          if (t + 1 < c1) {
            const int kc2 = (t + 1) * 64;
#pragma unroll
            for (int j = 0; j < 16; j++)
              gload16(krow0 + (size_t)((kc2 + w * 16 + j) * 4) * 1024,
                      &Ks[1 - p][(w * 16 + j) * 520]);
          }
          f32x4 S0 = {}, S1 = {}, S2 = {}, S3 = {};
#pragma unroll
          for (int kk = 0; kk < 16; kk++) {
            const bf16x8 k0 = *(const bf16x8*)&Ks[p][lr * 520 + kk * 32 + q * 8];
            const bf16x8 k1 = *(const bf16x8*)&Ks[p][(16 + lr) * 520 + kk * 32 + q * 8];
            const bf16x8 k2 = *(const bf16x8*)&Ks[p][(32 + lr) * 520 + kk * 32 + q * 8];
            const bf16x8 k3 = *(const bf16x8*)&Ks[p][(48 + lr) * 520 + kk * 32 + q * 8];
            S0 = MFMA16x16x32(Qf[kk], k0, S0);
            S1 = MFMA16x16x32(Qf[kk], k1, S1);
            S2 = MFMA16x16x32(Qf[kk], k2, S2);
            S3 = MFMA16x16x32(Qf[kk], k3, S3);
          }
#pragma unroll
          for (int r = 0; r < 4; r++) {
            const int row = myrow + r;
            const float p0 = (kc + lr > row) ? 0.f : __expf(S0[r] * sc);
            const float p1 = (kc + 16 + lr > row) ? 0.f : __expf(S1[r] * sc);
            const float p2 = (kc + 32 + lr > row) ? 0.f : __expf(S2[r] * sc);
            const float p3 = (kc + 48 + lr > row) ? 0.f : __expf(S3[r] * sc);
            bf16* pr = &Ps[p][w][(q * 4 + r) * 72];
            pr[lr] = (bf16)p0;
            pr[16 + lr] = (bf16)p1;
            pr[32 + lr] = (bf16)p2;
            pr[48 + lr] = (bf16)p3;
          }
        }
        __syncthreads();  // [Bt] P[t] visible; K[t+1] landed; P[t-1] reads done
      }
    }
  } else {
    // ================= PV-waves =================
    const int pw = w - 4;  // 0..7, dims [64*pw, 64*pw+64)
    bf16x8 ones;
#pragma unroll
    for (int e = 0; e < 8; e++) ones[e] = (bf16)1.0f;
    const bf16* vbase = vtg + ((size_t)bh << 20) + (size_t)(pw * 64 + lr) * 2048 + q * 8;
    for (int piece = 0; piece < 2; ++piece) {
      const int qt = piece ? (31 - y) : y;
      const int qrow0 = qt * 64;
      const int nc = qt + 1;
      const int hs = (nc + 1) >> 1;
      const int c0 = piece ? hs : 0;
      const int c1 = piece ? nc : hs;
      f32x4 O[4][4] = {};
      f32x4 lac = {};
      __syncthreads();  // [B0]
      for (int t = c0; t <= c1; t++) {
        if (t > c0) {
          const int p = (t - 1) & 1;
          const int kc = (t - 1) * 64;
#pragma unroll
          for (int s = 0; s < 2; s++) {
            bf16x8 pa[4];
#pragma unroll
            for (int rt = 0; rt < 4; rt++)
              pa[rt] = *(const bf16x8*)&Ps[p][rt][lr * 72 + s * 32 + q * 8];
            if (pw < 4) {
              // static select (avoid runtime-indexed register array -> scratch)
              const bf16x8 psel = pw == 0 ? pa[0] : (pw == 1 ? pa[1] : (pw == 2 ? pa[2] : pa[3]));
              lac = MFMA16x16x32(psel, ones, lac);
            }
#pragma unroll
            for (int ct = 0; ct < 4; ct++) {
              const bf16x8 vf = *(const bf16x8*)(vbase + (size_t)(ct * 16) * 2048 + kc + s * 32);
#pragma unroll
              for (int rt = 0; rt < 4; rt++)
                O[rt][ct] = MFMA16x16x32(pa[rt], vf, O[rt][ct]);
            }
          }
        }
        __syncthreads();  // [Bt]
      }
      // ---- write partials: opart[half][bh][row 2048][dim 512] (= d_out) ----
      bf16* op = opart + (size_t)piece * (8u << 20) + (size_t)bh * (1u << 20);
#pragma unroll
      for (int rt = 0; rt < 4; rt++)
#pragma unroll
        for (int ct = 0; ct < 4; ct++)
#pragma unroll
          for (int r = 0; r < 4; r++)
            op[(size_t)(qrow0 + rt * 16 + q * 4 + r) * 512 + pw * 64 + ct * 16 + lr] =
                (bf16)O[rt][ct][r];
      if (lr == 0 && pw < 4) {
#pragma unroll
        for (int r = 0; r < 4; r++)
          lpart[piece * 16384 + bh * 2048 + qrow0 + pw * 16 + q * 4 + r] = lac[r];
      }
    }
  }
}

// ---------------- combine: ctx = (O0+O1)/(l0+l1), bf16 token-major ---------
__global__ __launch_bounds__(256) void attn_combine(
    const bf16* __restrict__ opart, const float* __restrict__ lpart,
    bf16* __restrict__ ctx)
{
  const int gid = blockIdx.x * 256 + threadIdx.x;
  const int bh = gid >> 17;
  const int rem = gid & 131071;
  const int row = rem >> 6;
  const int dc = (rem & 63) * 8;
  const size_t o = (size_t)bh * (1u << 20) + (size_t)row * 512 + dc;
  const bf16x8 a = *(const bf16x8*)(opart + o);
  const bf16x8 c = *(const bf16x8*)(opart + (size_t)(8u << 20) + o);
  const float inv = 1.0f /
      (lpart[bh * 2048 + row] + lpart[16384 + bh * 2048 + row]);
  bf16x8 ov;
#pragma unroll
  for (int e = 0; e < 8; e++) ov[e] = (bf16)(((float)a[e] + (float)c[e]) * inv);
  const int b = bh >> 1, h = bh & 1;
  *(bf16x8*)(ctx + (size_t)(row * 4 + b) * 1024 + h * 512 + dc) = ov;
}

// ---------------------------------------------------------------------------
extern "C" void kernel_launch(void* const* d_in, const int* in_sizes, int n_in,
                              void* d_out, int out_size, void* d_ws, size_t ws_size,
                              hipStream_t stream)
{
  (void)in_sizes; (void)n_in; (void)out_size; (void)ws_size;
  const float* x    = (const float*)d_in[0];
  const float* wn1  = (const float*)d_in[1];
  const float* wqkv = (const float*)d_in[2];
  const float* bqkv = (const float*)d_in[3];
  const float* wout = (const float*)d_in[4];
  const float* bout = (const float*)d_in[5];
  const float* wn2  = (const float*)d_in[6];
  const float* W1   = (const float*)d_in[7];
  const float* b1   = (const float*)d_in[8];
  const float* W2   = (const float*)d_in[9];
  const float* b2   = (const float*)d_in[10];
  float* out = (float*)d_out;

  char* ws = (char*)d_ws;
  const size_t Mi = 1u << 20;
  bf16* S0v = (bf16*)(ws);              // h -> vt -> m
  bf16* S1v = (bf16*)(ws + 16 * Mi);    // q -> ctx
  bf16* S2v = (bf16*)(ws + 32 * Mi);    // k -> g (lower half)
  bf16* S3v = (bf16*)(ws + 48 * Mi);    // vtmp -> l -> g (upper half)
  bf16* wqb = (bf16*)(ws + 64 * Mi);
  bf16* wob = (bf16*)(ws + 70 * Mi);
  bf16* w1b = (bf16*)(ws + 72 * Mi);
  bf16* w2b = (bf16*)(ws + 76 * Mi);
  const int M = 8192;

  wcvt4<<<8192, 256, 0, stream>>>(wqkv, wqb, wout, wob, W1, w1b, W2, w2b);
  rmsnorm_kernel<<<8192, 256, 0, stream>>>(x, wn1, S0v);
  gemm_bt2<EPI_QKV><<<64 * 24, 256, 0, stream>>>(
      S0v, wqb, bqkv, nullptr, nullptr, S1v, S2v, S3v, M, 3072, 1024);
  vtrans_kernel<<<dim3(32, 8, 8), 256, 0, stream>>>(S3v, S0v);
  attn_kernel<<<dim3(8, 32), 768, 0, stream>>>(
      S1v, S2v, S0v, (bf16*)d_out, (float*)S3v);
  attn_combine<<<4096, 256, 0, stream>>>((const bf16*)d_out, (const float*)S3v, S1v);
  gemm_bt2<EPI_RES><<<64 * 8, 256, 0, stream>>>(
      S1v, wob, bout, x, out, nullptr, nullptr, nullptr, M, 1024, 1024);
  rmsnorm_kernel<<<8192, 256, 0, stream>>>(out, wn2, S0v);
  gemm_bt2<EPI_GELU><<<64 * 16, 256, 0, stream>>>(
      S0v, w1b, b1, nullptr, nullptr, S2v, nullptr, nullptr, M, 2048, 1024);
  gemm_bt2<EPI_RES><<<64 * 8, 256, 0, stream>>>(
      S2v, w2b, b2, out, out, nullptr, nullptr, nullptr, M, 1024, 2048);
}